// Round 3
// baseline (126.401 us; speedup 1.0000x reference)
//
#include <hip/hip_runtime.h>

#define NROW 4096
#define DIM  512
#define NT   32   // 4096 / 128 tiles per dimension

using short8 = __attribute__((ext_vector_type(8))) short;
using f32x4  = __attribute__((ext_vector_type(4))) float;

__device__ __forceinline__ unsigned short f2bf(float f) {
  unsigned u = __float_as_uint(f);
  u += 0x7FFFu + ((u >> 16) & 1u);          // round-to-nearest-even
  return (unsigned short)(u >> 16);
}
__device__ __forceinline__ float bf2f(unsigned short s) {
  return __uint_as_float(((unsigned)s) << 16);
}

// ---------- prep: fp32 -> bf16 bits, row squared norms, zero accumulators ----------
__global__ void __launch_bounds__(256) prep_kernel(
    const float* __restrict__ X, const float* __restrict__ Y,
    unsigned short* __restrict__ Xb, unsigned short* __restrict__ Yb,
    float* __restrict__ sqx, float* __restrict__ sqy,
    float* __restrict__ acc /* rK[4096] rL[4096] S1[1] */) {
  int tid = threadIdx.x;
  if (blockIdx.x == 0) {
    for (int i = tid; i < 2 * NROW + 1; i += 256) acc[i] = 0.f;
  }
  int lane = tid & 63, w = tid >> 6;
  int row = blockIdx.x * 4 + w;

  {
    const float* xr = X + (size_t)row * DIM;
    unsigned short* xo = Xb + (size_t)row * DIM;
    float s = 0.f;
#pragma unroll
    for (int it = 0; it < 2; ++it) {
      int k = it * 256 + lane * 4;
      float4 v = *reinterpret_cast<const float4*>(xr + k);
      ushort4 o;
      o.x = f2bf(v.x); o.y = f2bf(v.y); o.z = f2bf(v.z); o.w = f2bf(v.w);
      float f0 = bf2f(o.x), f1 = bf2f(o.y), f2 = bf2f(o.z), f3 = bf2f(o.w);
      s += f0 * f0 + f1 * f1 + f2 * f2 + f3 * f3;
      *reinterpret_cast<ushort4*>(xo + k) = o;
    }
#pragma unroll
    for (int m = 1; m < 64; m <<= 1) s += __shfl_xor(s, m);
    if (lane == 0) sqx[row] = s;
  }
  {
    const float* yr = Y + (size_t)row * DIM;
    unsigned short* yo = Yb + (size_t)row * DIM;
    float s = 0.f;
#pragma unroll
    for (int it = 0; it < 2; ++it) {
      int k = it * 256 + lane * 4;
      float4 v = *reinterpret_cast<const float4*>(yr + k);
      ushort4 o;
      o.x = f2bf(v.x); o.y = f2bf(v.y); o.z = f2bf(v.z); o.w = f2bf(v.w);
      float f0 = bf2f(o.x), f1 = bf2f(o.y), f2 = bf2f(o.z), f3 = bf2f(o.w);
      s += f0 * f0 + f1 * f1 + f2 * f2 + f3 * f3;
      *reinterpret_cast<ushort4*>(yo + k) = o;
    }
#pragma unroll
    for (int m = 1; m < 64; m <<= 1) s += __shfl_xor(s, m);
    if (lane == 0) sqy[row] = s;
  }
}

// ---------- staging: global_load_lds width=16, linear LDS dest, ----------
// ---------- inverse-swizzled global source (rule #21 / T2)      ----------
__device__ __forceinline__ void stage_tile(unsigned short* lds,
                                           const unsigned short* gbase, // src + row0*DIM + k0
                                           int tid) {
  int w = tid >> 6;
#pragma unroll
  for (int p = 0; p < 4; ++p) {
    int q = p * 256 + tid;       // 16B chunk id, 0..1023 (128 rows x 8 chunks)
    int r = q >> 3;              // tile row
    int c = q & 7;               // chunk-in-row at the linear LDS slot
    int cs = c ^ (r & 7);        // source chunk (involution)
    const unsigned short* gp = gbase + r * DIM + cs * 8;
    unsigned short* lp = lds + (p * 256 + w * 64) * 8;  // wave-uniform base, +lane*16B by HW
    __builtin_amdgcn_global_load_lds(
        (const __attribute__((address_space(1))) void*)gp,
        (__attribute__((address_space(3))) void*)lp, 16, 0, 0);
  }
}

__device__ __forceinline__ void gemm_tiles(const unsigned short* __restrict__ src,
                                           int bi, int bj, int tid,
                                           unsigned short* At, unsigned short* Bt,
                                           f32x4 acc[4][4]) {
  int lane = tid & 63, w = tid >> 6;
  int wr = w >> 1, wc = w & 1;
  int lr = lane & 15, lg = lane >> 4;
  for (int kb = 0; kb < 8; ++kb) {
    stage_tile(At, src + (size_t)(bi * 128) * DIM + kb * 64, tid);
    stage_tile(Bt, src + (size_t)(bj * 128) * DIM + kb * 64, tid);
    __syncthreads();
#pragma unroll
    for (int kk = 0; kk < 2; ++kk) {
      short8 a[4], b[4];
#pragma unroll
      for (int m = 0; m < 4; ++m) {
        int ra = wr * 64 + m * 16 + lr;
        int ca = kk * 4 + lg;
        a[m] = *reinterpret_cast<const short8*>(At + (ra * 8 + (ca ^ (ra & 7))) * 8);
        int rb = wc * 64 + m * 16 + lr;
        b[m] = *reinterpret_cast<const short8*>(Bt + (rb * 8 + (ca ^ (rb & 7))) * 8);
      }
#pragma unroll
      for (int m = 0; m < 4; ++m)
#pragma unroll
        for (int n = 0; n < 4; ++n)
          acc[m][n] = __builtin_amdgcn_mfma_f32_16x16x32_bf16(a[m], b[n], acc[m][n], 0, 0, 0);
    }
    __syncthreads();
  }
}

// ---------- gram: dual Gram GEMM (upper triangle) + fused RBF/reduction epilogue ----------
__global__ void __launch_bounds__(256, 2) gram_kernel(
    const unsigned short* __restrict__ Xb, const unsigned short* __restrict__ Yb,
    const float* __restrict__ sqx, const float* __restrict__ sqy,
    float* __restrict__ rK, float* __restrict__ rL, float* __restrict__ S1) {
  __shared__ unsigned short At[128 * 64];
  __shared__ unsigned short Bt[128 * 64];
  __shared__ float s1buf[4];

  int tid = threadIdx.x;
  // decode upper-triangular tile pair
  int t = blockIdx.x, bi = 0;
  while (t >= NT - bi) { t -= NT - bi; ++bi; }
  int bj = bi + t;

  f32x4 accK[4][4], accL[4][4];
  f32x4 zz = {0.f, 0.f, 0.f, 0.f};
#pragma unroll
  for (int m = 0; m < 4; ++m)
#pragma unroll
    for (int n = 0; n < 4; ++n) { accK[m][n] = zz; accL[m][n] = zz; }

  gemm_tiles(Xb, bi, bj, tid, At, Bt, accK);
  gemm_tiles(Yb, bi, bj, tid, At, Bt, accL);

  // ---- epilogue: k = exp(-d2/2), fused S1 / row sums / (symmetric) col sums ----
  int lane = tid & 63, w = tid >> 6;
  int wr = w >> 1, wc = w & 1;
  int lr = lane & 15, lg = lane >> 4;

  float ckx[4] = {0.f, 0.f, 0.f, 0.f};   // column partials (K)
  float cky[4] = {0.f, 0.f, 0.f, 0.f};   // column partials (L)
  float sjx[4], sjy[4]; int gj[4];
#pragma unroll
  for (int n = 0; n < 4; ++n) {
    gj[n] = bj * 128 + wc * 64 + n * 16 + lr;
    sjx[n] = sqx[gj[n]];
    sjy[n] = sqy[gj[n]];
  }
  float s1loc = 0.f;
#pragma unroll
  for (int m = 0; m < 4; ++m) {
#pragma unroll
    for (int r = 0; r < 4; ++r) {
      int gi = bi * 128 + wr * 64 + m * 16 + lg * 4 + r;   // C layout: row=(lane>>4)*4+reg
      float six = sqx[gi], siy = sqy[gi];
      float rowk = 0.f, rowl = 0.f;
#pragma unroll
      for (int n = 0; n < 4; ++n) {
        float gk = accK[m][n][r];
        float gl = accL[m][n][r];
        float kv, lv;
        if (gi == gj[n]) {               // exact diagonal: d2 == 0
          kv = 1.f; lv = 1.f;
        } else {
          kv = __expf(-0.5f * fmaxf(six + sjx[n] - 2.f * gk, 0.f));
          lv = __expf(-0.5f * fmaxf(siy + sjy[n] - 2.f * gl, 0.f));
        }
        s1loc += kv * lv;
        rowk += kv; rowl += lv;
        ckx[n] += kv; cky[n] += lv;
      }
      // reduce this row's 16 column-lanes
#pragma unroll
      for (int msk = 1; msk < 16; msk <<= 1) {
        rowk += __shfl_xor(rowk, msk);
        rowl += __shfl_xor(rowl, msk);
      }
      if (lr == 0) { atomicAdd(&rK[gi], rowk); atomicAdd(&rL[gi], rowl); }
    }
  }
  if (bi != bj) {
    // symmetric contribution: column sums of this tile -> rows of the bj block
#pragma unroll
    for (int n = 0; n < 4; ++n) {
      float a = ckx[n], b = cky[n];
      a += __shfl_xor(a, 16); a += __shfl_xor(a, 32);
      b += __shfl_xor(b, 16); b += __shfl_xor(b, 32);
      if (lg == 0) { atomicAdd(&rK[gj[n]], a); atomicAdd(&rL[gj[n]], b); }
    }
    s1loc *= 2.f;
  }
#pragma unroll
  for (int msk = 1; msk < 64; msk <<= 1) s1loc += __shfl_xor(s1loc, msk);
  if (lane == 0) s1buf[w] = s1loc;
  __syncthreads();
  if (tid == 0) atomicAdd(S1, s1buf[0] + s1buf[1] + s1buf[2] + s1buf[3]);
}

// ---------- finalize: S2/SK/SL + closed-form HSIC ----------
__global__ void __launch_bounds__(256) finalize_kernel(
    const float* __restrict__ acc, float* __restrict__ out) {
  const float* rK = acc;
  const float* rL = acc + NROW;
  const float* S1 = acc + 2 * NROW;
  int tid = threadIdx.x, lane = tid & 63, w = tid >> 6;
  float sk = 0.f, sl = 0.f, s2 = 0.f;
  for (int i = tid; i < NROW; i += 256) {
    float a = rK[i], b = rL[i];
    sk += a; sl += b; s2 += a * b;
  }
#pragma unroll
  for (int m = 1; m < 64; m <<= 1) {
    sk += __shfl_xor(sk, m);
    sl += __shfl_xor(sl, m);
    s2 += __shfl_xor(s2, m);
  }
  __shared__ float bk[4], bl[4], b2[4];
  if (lane == 0) { bk[w] = sk; bl[w] = sl; b2[w] = s2; }
  __syncthreads();
  if (tid == 0) {
    double SK = (double)bk[0] + bk[1] + bk[2] + bk[3];
    double SL = (double)bl[0] + bl[1] + bl[2] + bl[3];
    double S2 = (double)b2[0] + b2[1] + b2[2] + b2[3];
    double s1 = (double)S1[0];
    double n = (double)NROW;
    out[0] = (float)((s1 - 2.0 * S2 / n + SK * SL / (n * n)) / (n * n));
  }
}

extern "C" void kernel_launch(void* const* d_in, const int* in_sizes, int n_in,
                              void* d_out, int out_size, void* d_ws, size_t ws_size,
                              hipStream_t stream) {
  (void)in_sizes; (void)n_in; (void)out_size; (void)ws_size;
  const float* X = (const float*)d_in[0];
  const float* Y = (const float*)d_in[1];

  unsigned short* Xb = (unsigned short*)d_ws;                 // 4 MB
  unsigned short* Yb = Xb + (size_t)NROW * DIM;               // 4 MB
  float* sqx = (float*)(Yb + (size_t)NROW * DIM);             // 16 KB
  float* sqy = sqx + NROW;                                    // 16 KB
  float* acc = sqy + NROW;                                    // rK | rL | S1

  prep_kernel<<<NROW / 4, 256, 0, stream>>>(X, Y, Xb, Yb, sqx, sqy, acc);
  gram_kernel<<<NT * (NT + 1) / 2, 256, 0, stream>>>(Xb, Yb, sqx, sqy,
                                                     acc, acc + NROW, acc + 2 * NROW);
  finalize_kernel<<<1, 256, 0, stream>>>(acc, (float*)d_out);
}

// Round 4
// 116.608 us; speedup vs baseline: 1.0840x; 1.0840x over previous
//
#include <hip/hip_runtime.h>

#define NROW 4096
#define DIM  512
#define NT   32   // 4096 / 128 tiles per dimension

using short8 = __attribute__((ext_vector_type(8))) short;
using f32x4  = __attribute__((ext_vector_type(4))) float;

__device__ __forceinline__ unsigned short f2bf(float f) {
  unsigned u = __float_as_uint(f);
  u += 0x7FFFu + ((u >> 16) & 1u);          // round-to-nearest-even
  return (unsigned short)(u >> 16);
}
__device__ __forceinline__ float bf2f(unsigned short s) {
  return __uint_as_float(((unsigned)s) << 16);
}

// ---------- prep: fp32 -> bf16 bits, row squared norms, zero accumulators ----------
__global__ void __launch_bounds__(256) prep_kernel(
    const float* __restrict__ X, const float* __restrict__ Y,
    unsigned short* __restrict__ Xb, unsigned short* __restrict__ Yb,
    float* __restrict__ sqx, float* __restrict__ sqy,
    float* __restrict__ acc /* rK[4096] rL[4096] S1[1] */) {
  int tid = threadIdx.x;
  if (blockIdx.x == 0) {
    for (int i = tid; i < 2 * NROW + 1; i += 256) acc[i] = 0.f;
  }
  int lane = tid & 63, w = tid >> 6;
  int row = blockIdx.x * 4 + w;

  {
    const float* xr = X + (size_t)row * DIM;
    unsigned short* xo = Xb + (size_t)row * DIM;
    float s = 0.f;
#pragma unroll
    for (int it = 0; it < 2; ++it) {
      int k = it * 256 + lane * 4;
      float4 v = *reinterpret_cast<const float4*>(xr + k);
      ushort4 o;
      o.x = f2bf(v.x); o.y = f2bf(v.y); o.z = f2bf(v.z); o.w = f2bf(v.w);
      float f0 = bf2f(o.x), f1 = bf2f(o.y), f2 = bf2f(o.z), f3 = bf2f(o.w);
      s += f0 * f0 + f1 * f1 + f2 * f2 + f3 * f3;
      *reinterpret_cast<ushort4*>(xo + k) = o;
    }
#pragma unroll
    for (int m = 1; m < 64; m <<= 1) s += __shfl_xor(s, m);
    if (lane == 0) sqx[row] = s;
  }
  {
    const float* yr = Y + (size_t)row * DIM;
    unsigned short* yo = Yb + (size_t)row * DIM;
    float s = 0.f;
#pragma unroll
    for (int it = 0; it < 2; ++it) {
      int k = it * 256 + lane * 4;
      float4 v = *reinterpret_cast<const float4*>(yr + k);
      ushort4 o;
      o.x = f2bf(v.x); o.y = f2bf(v.y); o.z = f2bf(v.z); o.w = f2bf(v.w);
      float f0 = bf2f(o.x), f1 = bf2f(o.y), f2 = bf2f(o.z), f3 = bf2f(o.w);
      s += f0 * f0 + f1 * f1 + f2 * f2 + f3 * f3;
      *reinterpret_cast<ushort4*>(yo + k) = o;
    }
#pragma unroll
    for (int m = 1; m < 64; m <<= 1) s += __shfl_xor(s, m);
    if (lane == 0) sqy[row] = s;
  }
}

// ---------- staging: global_load_lds width=16, linear LDS dest, ----------
// ---------- inverse-swizzled global source (rule #21 / T2)      ----------
__device__ __forceinline__ void stage_tile(unsigned short* lds,
                                           const unsigned short* gbase, // src + row0*DIM + k0
                                           int tid) {
  int w = tid >> 6;
#pragma unroll
  for (int p = 0; p < 4; ++p) {
    int q = p * 256 + tid;       // 16B chunk id, 0..1023 (128 rows x 8 chunks)
    int r = q >> 3;              // tile row
    int c = q & 7;               // chunk-in-row at the linear LDS slot
    int cs = c ^ (r & 7);        // source chunk (involution)
    const unsigned short* gp = gbase + r * DIM + cs * 8;
    unsigned short* lp = lds + (p * 256 + w * 64) * 8;  // wave-uniform base, +lane*16B by HW
    __builtin_amdgcn_global_load_lds(
        (const __attribute__((address_space(1))) void*)gp,
        (__attribute__((address_space(3))) void*)lp, 16, 0, 0);
  }
}

// 32 MFMAs on one staged (A,B) tile pair (K=64), swizzled ds_read_b128
__device__ __forceinline__ void tile_mfma(const unsigned short* At, const unsigned short* Bt,
                                          int lr, int lg, int wr, int wc,
                                          f32x4 acc[4][4]) {
#pragma unroll
  for (int kk = 0; kk < 2; ++kk) {
    short8 a[4], b[4];
#pragma unroll
    for (int m = 0; m < 4; ++m) {
      int ra = wr * 64 + m * 16 + lr;
      int ca = kk * 4 + lg;
      a[m] = *reinterpret_cast<const short8*>(At + (ra * 8 + (ca ^ (ra & 7))) * 8);
      int rb = wc * 64 + m * 16 + lr;
      b[m] = *reinterpret_cast<const short8*>(Bt + (rb * 8 + (ca ^ (rb & 7))) * 8);
    }
#pragma unroll
    for (int m = 0; m < 4; ++m)
#pragma unroll
      for (int n = 0; n < 4; ++n)
        acc[m][n] = __builtin_amdgcn_mfma_f32_16x16x32_bf16(a[m], b[n], acc[m][n], 0, 0, 0);
  }
}

// ---------- gram: dual Gram GEMM (upper triangle), 2-phase double-buffered ----------
__global__ void __launch_bounds__(256, 2) gram_kernel(
    const unsigned short* __restrict__ Xb, const unsigned short* __restrict__ Yb,
    const float* __restrict__ sqx, const float* __restrict__ sqy,
    float* __restrict__ rK, float* __restrict__ rL, float* __restrict__ S1) {
  __shared__ unsigned short lds[2][2][128 * 64];   // [buf][A|B][tile] = 64 KB
  __shared__ float s1buf[4];

  int tid = threadIdx.x;
  // XCD-aware bijective swizzle: 528 blocks = 8 XCDs x 66
  int wg = (blockIdx.x & 7) * 66 + (blockIdx.x >> 3);
  // decode upper-triangular tile pair
  int t = wg, bi = 0;
  while (t >= NT - bi) { t -= NT - bi; ++bi; }
  int bj = bi + t;

  int lane = tid & 63, w = tid >> 6;
  int wr = w >> 1, wc = w & 1;
  int lr = lane & 15, lg = lane >> 4;

  f32x4 accK[4][4], accL[4][4];
  f32x4 zz = {0.f, 0.f, 0.f, 0.f};
#pragma unroll
  for (int m = 0; m < 4; ++m)
#pragma unroll
    for (int n = 0; n < 4; ++n) { accK[m][n] = zz; accL[m][n] = zz; }

  const size_t rowA = (size_t)(bi * 128) * DIM;
  const size_t rowB = (size_t)(bj * 128) * DIM;

  // stage step `it` (0..15): it>>3 selects X/Y gram, it&7 selects K-block
  auto stage_pair = [&](int it) {
    const unsigned short* src = (it & 8) ? Yb : Xb;
    int kb = it & 7;
    stage_tile(lds[it & 1][0], src + rowA + kb * 64, tid);
    stage_tile(lds[it & 1][1], src + rowB + kb * 64, tid);
  };

  // prologue
  stage_pair(0);
  __syncthreads();
  // X gram: compute it, prefetch it+1 (it+1==8 prefetches Y kb0)
#pragma unroll
  for (int kb = 0; kb < 8; ++kb) {
    stage_pair(kb + 1);
    tile_mfma(lds[kb & 1][0], lds[kb & 1][1], lr, lg, wr, wc, accK);
    __syncthreads();
  }
  // Y gram
#pragma unroll
  for (int kb = 0; kb < 8; ++kb) {
    if (kb < 7) stage_pair(8 + kb + 1);
    tile_mfma(lds[kb & 1][0], lds[kb & 1][1], lr, lg, wr, wc, accL);
    __syncthreads();
  }

  // ---- epilogue: k = exp(-d2/2), fused S1 / row sums / (symmetric) col sums ----
  float ckx[4] = {0.f, 0.f, 0.f, 0.f};   // column partials (K)
  float cky[4] = {0.f, 0.f, 0.f, 0.f};   // column partials (L)
  float sjx[4], sjy[4]; int gj[4];
#pragma unroll
  for (int n = 0; n < 4; ++n) {
    gj[n] = bj * 128 + wc * 64 + n * 16 + lr;
    sjx[n] = sqx[gj[n]];
    sjy[n] = sqy[gj[n]];
  }
  float s1loc = 0.f;
#pragma unroll
  for (int m = 0; m < 4; ++m) {
#pragma unroll
    for (int r = 0; r < 4; ++r) {
      int gi = bi * 128 + wr * 64 + m * 16 + lg * 4 + r;   // C layout: row=(lane>>4)*4+reg
      float six = sqx[gi], siy = sqy[gi];
      float rowk = 0.f, rowl = 0.f;
#pragma unroll
      for (int n = 0; n < 4; ++n) {
        float gk = accK[m][n][r];
        float gl = accL[m][n][r];
        float kv, lv;
        if (gi == gj[n]) {               // exact diagonal: d2 == 0
          kv = 1.f; lv = 1.f;
        } else {
          kv = __expf(-0.5f * fmaxf(six + sjx[n] - 2.f * gk, 0.f));
          lv = __expf(-0.5f * fmaxf(siy + sjy[n] - 2.f * gl, 0.f));
        }
        s1loc += kv * lv;
        rowk += kv; rowl += lv;
        ckx[n] += kv; cky[n] += lv;
      }
      // reduce this row's 16 column-lanes
#pragma unroll
      for (int msk = 1; msk < 16; msk <<= 1) {
        rowk += __shfl_xor(rowk, msk);
        rowl += __shfl_xor(rowl, msk);
      }
      if (lr == 0) { atomicAdd(&rK[gi], rowk); atomicAdd(&rL[gi], rowl); }
    }
  }
  if (bi != bj) {
    // symmetric contribution: column sums of this tile -> rows of the bj block
#pragma unroll
    for (int n = 0; n < 4; ++n) {
      float a = ckx[n], b = cky[n];
      a += __shfl_xor(a, 16); a += __shfl_xor(a, 32);
      b += __shfl_xor(b, 16); b += __shfl_xor(b, 32);
      if (lg == 0) { atomicAdd(&rK[gj[n]], a); atomicAdd(&rL[gj[n]], b); }
    }
    s1loc *= 2.f;
  }
#pragma unroll
  for (int msk = 1; msk < 64; msk <<= 1) s1loc += __shfl_xor(s1loc, msk);
  if (lane == 0) s1buf[w] = s1loc;
  __syncthreads();
  if (tid == 0) atomicAdd(S1, s1buf[0] + s1buf[1] + s1buf[2] + s1buf[3]);
}

// ---------- finalize: S2/SK/SL + closed-form HSIC ----------
__global__ void __launch_bounds__(1024) finalize_kernel(
    const float* __restrict__ acc, float* __restrict__ out) {
  const float* rK = acc;
  const float* rL = acc + NROW;
  const float* S1 = acc + 2 * NROW;
  int tid = threadIdx.x, lane = tid & 63, w = tid >> 6;   // 16 waves
  float4 a = reinterpret_cast<const float4*>(rK)[tid];    // 1024 x float4 = 4096 floats
  float4 b = reinterpret_cast<const float4*>(rL)[tid];
  float sk = a.x + a.y + a.z + a.w;
  float sl = b.x + b.y + b.z + b.w;
  float s2 = a.x * b.x + a.y * b.y + a.z * b.z + a.w * b.w;
#pragma unroll
  for (int m = 1; m < 64; m <<= 1) {
    sk += __shfl_xor(sk, m);
    sl += __shfl_xor(sl, m);
    s2 += __shfl_xor(s2, m);
  }
  __shared__ float bk[16], bl[16], b2[16];
  if (lane == 0) { bk[w] = sk; bl[w] = sl; b2[w] = s2; }
  __syncthreads();
  if (tid == 0) {
    double SK = 0.0, SL = 0.0, S2 = 0.0;
#pragma unroll
    for (int i = 0; i < 16; ++i) { SK += bk[i]; SL += bl[i]; S2 += b2[i]; }
    double s1 = (double)S1[0];
    double n = (double)NROW;
    out[0] = (float)((s1 - 2.0 * S2 / n + SK * SL / (n * n)) / (n * n));
  }
}

extern "C" void kernel_launch(void* const* d_in, const int* in_sizes, int n_in,
                              void* d_out, int out_size, void* d_ws, size_t ws_size,
                              hipStream_t stream) {
  (void)in_sizes; (void)n_in; (void)out_size; (void)ws_size;
  const float* X = (const float*)d_in[0];
  const float* Y = (const float*)d_in[1];

  unsigned short* Xb = (unsigned short*)d_ws;                 // 4 MB
  unsigned short* Yb = Xb + (size_t)NROW * DIM;               // 4 MB
  float* sqx = (float*)(Yb + (size_t)NROW * DIM);             // 16 KB
  float* sqy = sqx + NROW;                                    // 16 KB
  float* acc = sqy + NROW;                                    // rK | rL | S1

  prep_kernel<<<NROW / 4, 256, 0, stream>>>(X, Y, Xb, Yb, sqx, sqy, acc);
  gram_kernel<<<NT * (NT + 1) / 2, 256, 0, stream>>>(Xb, Yb, sqx, sqy,
                                                     acc, acc + NROW, acc + 2 * NROW);
  finalize_kernel<<<1, 1024, 0, stream>>>(acc, (float*)d_out);
}